// Round 2
// baseline (325.858 us; speedup 1.0000x reference)
//
#include <hip/hip_runtime.h>

// Problem constants
#define D 32
#define K 8
#define NPAIR 36

// ws layout (float offsets)
#define MOFF 0                 // invLc, 8 x 32 x 32 row-major, upper triangle zeroed
#define WOFF 8192              // w_k = invLc_k mu_k, 8 x 32
#define C2OFF 8448             // (c'_t - cmax) * log2(e), 36
#define CMAXOFF 8484
#define LCOFF 8512             // Lc (cholesky factors), 8 x 32 x 32, upper zeroed
#define PARTOFF 16704          // per-block partial sums (512)

typedef float v2f __attribute__((ext_vector_type(2)));

__host__ __device__ constexpr int gidx(int i, int j) {  // i<=j packed index
    return i * 8 + j - i * (i + 1) / 2;
}

// ---------------------------------------------------------------------------
// setup1: one wave per cluster k. All linear algebra in registers + shuffles;
// every loop has compile-time bounds (no runtime-trip LDS chains).
// Lane i holds row i (lanes 32-63 compute duplicates/zeros, stores masked).
// ---------------------------------------------------------------------------
__global__ __launch_bounds__(64) void setup1_kernel(
    const float* __restrict__ mu, const float* __restrict__ L,
    float* __restrict__ ws)
{
    const int k = blockIdx.x;
    const int lane = threadIdx.x;       // 0..63; rows live in lanes 0..31
    const int row = lane & 31;

    // load row `row` of L_k (128B contiguous per lane)
    float l[D];
    {
        const float4* Lr = (const float4*)(L + k * D * D + row * D);
        #pragma unroll
        for (int q = 0; q < 8; ++q) {
            const float4 t = Lr[q];
            l[4 * q + 0] = t.x; l[4 * q + 1] = t.y;
            l[4 * q + 2] = t.z; l[4 * q + 3] = t.w;
        }
    }

    // A row: a[c] = sum_b l[b] * L[c][b] + (lane==c)   (A symmetric, full row valid)
    float a[D];
    #pragma unroll
    for (int c = 0; c < D; ++c) {
        float s = (lane == c) ? 1.0f : 0.0f;
        #pragma unroll
        for (int b = 0; b < D; ++b) s = fmaf(l[b], __shfl(l[b], c, 64), s);
        a[c] = s;
    }

    // Right-looking Cholesky: at step j, lanes c>j still hold valid rows.
    float lc[D];
    #pragma unroll
    for (int j = 0; j < D; ++j) {
        const float pivot = __shfl(a[j], j, 64);
        const float ljj = sqrtf(pivot);
        const float lij = a[j] / ljj;     // valid for lane>=j
        lc[j] = lij;
        #pragma unroll
        for (int c = j + 1; c < D; ++c)
            a[c] = fmaf(-lij, __shfl(lij, c, 64), a[c]);
    }

    // invLc: lane j solves column j (col[i]=0 for i<j by induction -> no predication)
    float col[D];
    #pragma unroll
    for (int i = 0; i < D; ++i) {
        float s = (lane == i) ? 1.0f : 0.0f;
        #pragma unroll
        for (int b = 0; b < i; ++b)
            s = fmaf(-__shfl(lc[b], i, 64), col[b], s);
        col[i] = s / __shfl(lc[i], i, 64);
    }

    // stores (lanes 0..31 only)
    if (lane < 32) {
        // invLc rows: element [i][j] lives at lane j -> coalesced per i
        #pragma unroll
        for (int i = 0; i < D; ++i)
            ws[MOFF + k * D * D + i * D + lane] = col[i];
        // Lc row `lane`, upper triangle zeroed (contiguous 128B per lane)
        #pragma unroll
        for (int j = 0; j < D; ++j) {
            const float v = (j <= lane) ? lc[j] : 0.0f;
            ws[LCOFF + k * D * D + lane * D + j] = v;
        }
    }

    // w_k[i] = sum_j invLc[i][j] mu[j]  (column j at lane j)
    {
        const float m = (lane < 32) ? mu[k * D + lane] : 0.0f;
        #pragma unroll
        for (int i = 0; i < D; ++i) {
            float t = col[i] * m;
            t += __shfl_xor(t, 1, 64);  t += __shfl_xor(t, 2, 64);
            t += __shfl_xor(t, 4, 64);  t += __shfl_xor(t, 8, 64);
            t += __shfl_xor(t, 16, 64);                 // sums lanes 0..31 half
            if (lane == 0) ws[WOFF + k * D + i] = t;
        }
    }
}

// ---------------------------------------------------------------------------
// setup2: pair constants. Stage Lc into LDS, 36 threads do fully-unrolled
// forward solves (constant trip counts -> pipelined ds_reads).
// ---------------------------------------------------------------------------
#define SLC(k, r, c) sLc[(k) * 1024 + (r) * 32 + (c)]

__global__ __launch_bounds__(256) void setup2_kernel(
    const float* __restrict__ weights, float* __restrict__ ws)
{
    __shared__ float sLc[K * D * D];
    __shared__ float sLogw[K];
    __shared__ float sCp[NPAIR];
    __shared__ float sCmax;
    const int tid = threadIdx.x;

    {   // stage 32 KB of Lc
        const float4* src = (const float4*)(ws + LCOFF);
        float4* dst = (float4*)sLc;
        for (int i = tid; i < K * D * D / 4; i += 256) dst[i] = src[i];
    }
    if (tid == 0) {
        float m = -INFINITY;
        for (int i = 0; i < K; ++i) m = fmaxf(m, weights[i]);
        float s = 0.0f;
        for (int i = 0; i < K; ++i) s += expf(weights[i] - m);
        const float lse = m + logf(s);
        for (int i = 0; i < K; ++i) sLogw[i] = weights[i] - lse;
    }
    __syncthreads();

    if (tid < NPAIR) {
        int tt = tid, i = 0;
        while (tt >= (K - i)) { tt -= (K - i); ++i; }
        const int j = i + tt;
        const float LOG2PI = 1.8378770664093453f;
        float sumlogS = 0.0f, logdetsig = 0.0f;
        #pragma unroll
        for (int r = 0; r < D; ++r) {
            const float di = SLC(i, r, r), dj = SLC(j, r, r);
            sumlogS += logf(di + dj);
            logdetsig -= logf(1.0f / di + 1.0f / dj);
        }
        // quad = -0.5 dmu^T inv(S) dmu, S = Lc_i + Lc_j lower-tri, mu from ws? ->
        // dmu reconstructed from w? No: use mu via global (tiny). We stored only w;
        // recompute dmu from global mu pointer passed through ws is unavailable ->
        // read mu directly: stash pointer-free: dmu = Lc_i w_i' ... simpler: solve
        // with d0 = mu_i - mu_j read from ws-independent source: we pass mu in
        // weights? No. We store mu in LDS? -> read from ws: setup1 stored w only.
        // Instead: mu is an input to setup2 as well (see kernel_launch).
        float v[D];
        float quad_acc = 0.0f;
        #pragma unroll
        for (int r = 0; r < D; ++r) {
            const float d0 = ws[CMAXOFF + 1 + i * D + r] - ws[CMAXOFF + 1 + j * D + r];
            float s = d0;
            #pragma unroll
            for (int b = 0; b < r; ++b)
                s -= (SLC(i, r, b) + SLC(j, r, b)) * v[b];
            v[r] = s / (SLC(i, r, r) + SLC(j, r, r));
            quad_acc = fmaf(d0, v[r], quad_acc);
        }
        const float quad = -0.5f * quad_acc;
        float c = quad - 0.5f * sumlogS - (float)D * LOG2PI - 0.5f * logdetsig
                  + sLogw[i] + sLogw[j];
        if (i < j) c += 0.6931471805599453f;
        sCp[tid] = c;
    }
    __syncthreads();
    if (tid == 0) {
        float m = -INFINITY;
        for (int t = 0; t < NPAIR; ++t) m = fmaxf(m, sCp[t]);
        sCmax = m;
        ws[CMAXOFF] = m;
    }
    __syncthreads();
    if (tid < NPAIR)
        ws[C2OFF + tid] = (sCp[tid] - sCmax) * 1.4426950408889634f;
}

// tiny copy: mu -> ws[CMAXOFF+1 ..] so setup2 can read it (kept on stream)
__global__ void stash_mu_kernel(const float* __restrict__ mu, float* __restrict__ ws) {
    const int t = blockIdx.x * 64 + threadIdx.x;
    if (t < K * D) ws[CMAXOFF + 1 + t] = mu[t];
}

// ---------------------------------------------------------------------------
// main: lane = sample. M/w/c2 are wave-uniform -> scalar loads (SGPR) feeding
// v_pk_fma_f32 on float2 vectors. Zero LDS in the hot loop.
// y_k = invLc_k x - w_k, row-chunked (4 rows) so full y never materializes;
// Gram G accumulated in packed pairs.
// ---------------------------------------------------------------------------
__global__ __launch_bounds__(256) void main_kernel(
    const float* __restrict__ X, const float* __restrict__ cst,
    float* __restrict__ partials, int nsamp)
{
    __shared__ float sRed[4];
    const int tid = threadIdx.x;
    const int n = blockIdx.x * 256 + tid;
    float acc = 0.0f;

    if (n < nsamp) {
        v2f x[16];
        const float4* Xv = (const float4*)(X + n * D);
        #pragma unroll
        for (int q = 0; q < 8; ++q) {
            const float4 t = Xv[q];
            x[2 * q]     = (v2f){t.x, t.y};
            x[2 * q + 1] = (v2f){t.z, t.w};
        }

        v2f G2[NPAIR];
        #pragma unroll
        for (int t = 0; t < NPAIR; ++t) G2[t] = (v2f){0.0f, 0.0f};

        #pragma unroll
        for (int rh = 0; rh < 8; ++rh) {
            v2f y2[K][2];
            #pragma unroll
            for (int k = 0; k < K; ++k) {
                const float* Mk = cst + MOFF + k * D * D;
                const float* wk = cst + WOFF + k * D;
                #pragma unroll
                for (int rr = 0; rr < 4; ++rr) {
                    const int r = 4 * rh + rr;
                    v2f a = (v2f){-wk[r], 0.0f};          // uniform -> SGPR
                    const v2f* Mr = (const v2f*)(Mk + r * D);
                    #pragma unroll
                    for (int p = 0; p <= r / 2; ++p)      // trailing elem is 0-padded
                        a = __builtin_elementwise_fma(Mr[p], x[p], a);
                    const float yr = a.x + a.y;
                    if (rr & 1) y2[k][rr >> 1].y = yr;
                    else        y2[k][rr >> 1].x = yr;
                }
            }
            #pragma unroll
            for (int i = 0; i < K; ++i)
                #pragma unroll
                for (int j = i; j < K; ++j) {
                    v2f g = G2[gidx(i, j)];
                    g = __builtin_elementwise_fma(y2[i][0], y2[j][0], g);
                    g = __builtin_elementwise_fma(y2[i][1], y2[j][1], g);
                    G2[gidx(i, j)] = g;
                }
        }

        float G[NPAIR];
        #pragma unroll
        for (int t = 0; t < NPAIR; ++t) G[t] = G2[t].x + G2[t].y;

        const float* c2 = cst + C2OFF;
        const float NH = -0.72134752044448170f;           // -0.5*log2(e)
        #pragma unroll
        for (int i = 0; i < K; ++i)
            #pragma unroll
            for (int j = i; j < K; ++j) {
                const float q = fmaf(2.0f, G[gidx(i, j)], G[gidx(i, i)] + G[gidx(j, j)]);
                acc += exp2f(fmaf(NH, q, c2[gidx(i, j)]));
            }
    }

    #pragma unroll
    for (int m = 1; m < 64; m <<= 1) acc += __shfl_xor(acc, m, 64);
    if ((tid & 63) == 0) sRed[tid >> 6] = acc;
    __syncthreads();
    if (tid == 0) partials[blockIdx.x] = sRed[0] + sRed[1] + sRed[2] + sRed[3];
}

__global__ __launch_bounds__(256) void finish_kernel(
    const float* __restrict__ partials, const float* __restrict__ ws,
    float* __restrict__ out, int nblk)
{
    __shared__ float sRed[4];
    const int tid = threadIdx.x;
    float acc = 0.0f;
    for (int i = tid; i < nblk; i += 256) acc += partials[i];
    #pragma unroll
    for (int m = 1; m < 64; m <<= 1) acc += __shfl_xor(acc, m, 64);
    if ((tid & 63) == 0) sRed[tid >> 6] = acc;
    __syncthreads();
    if (tid == 0) out[0] = ws[CMAXOFF] + logf(sRed[0] + sRed[1] + sRed[2] + sRed[3]);
}

extern "C" void kernel_launch(void* const* d_in, const int* in_sizes, int n_in,
                              void* d_out, int out_size, void* d_ws, size_t ws_size,
                              hipStream_t stream) {
    const float* X = (const float*)d_in[0];
    const float* mu = (const float*)d_in[1];
    const float* L = (const float*)d_in[2];
    const float* w = (const float*)d_in[3];
    float* wsf = (float*)d_ws;
    float* out = (float*)d_out;

    const int nsamp = in_sizes[0] / D;
    const int nblk = (nsamp + 255) / 256;

    stash_mu_kernel<<<4, 64, 0, stream>>>(mu, wsf);
    setup1_kernel<<<K, 64, 0, stream>>>(mu, L, wsf);
    setup2_kernel<<<1, 256, 0, stream>>>(w, wsf);
    main_kernel<<<nblk, 256, 0, stream>>>(X, wsf, wsf + PARTOFF, nsamp);
    finish_kernel<<<1, 256, 0, stream>>>(wsf + PARTOFF, wsf, out, nblk);
}

// Round 3
// 158.124 us; speedup vs baseline: 2.0608x; 2.0608x over previous
//
#include <hip/hip_runtime.h>

// Problem constants
#define D 32
#define K 8
#define NPAIR 36

// ws layout (float offsets)
#define MOFF 0                 // invLc, 8 x 32 x 32 row-major, upper triangle zeroed
#define WOFF 8192              // w_k = invLc_k mu_k, 8 x 32
#define C2OFF 8448             // (c'_t - cmax) * log2(e), 36
#define CMAXOFF 8484
#define LCOFF 8512             // Lc (cholesky factors), 8 x 32 x 32, upper zeroed
#define PARTOFF 16704          // per-block partial sums (512)

typedef float v2f __attribute__((ext_vector_type(2)));

__host__ __device__ constexpr int gidx(int i, int j) {  // i<=j packed index
    return i * 8 + j - i * (i + 1) / 2;
}

// ---------------------------------------------------------------------------
// setup1: one block per cluster k, 64 threads (threads 32-63 duplicate work of
// tid&31 -- benign same-value LDS/global writes). All loops compile-time
// bounded after unroll; per-thread register arrays small (<=40 floats).
// ---------------------------------------------------------------------------
__global__ __launch_bounds__(64) void setup1_kernel(
    const float* __restrict__ mu, const float* __restrict__ L,
    float* __restrict__ ws)
{
    __shared__ float sA[D][D + 1];    // A = L L^T + I, later reused as invLc
    __shared__ float sLc[D][D + 1];   // published Cholesky rows
    const int k = blockIdx.x;
    const int tid = threadIdx.x;
    const int i = tid & 31;

    // A[a][c] = sum_b L[a][b] L[c][b] + (a==c); 16 elements per thread
    const float* Lk = L + k * D * D;
    for (int e = tid; e < D * D; e += 64) {
        const int a = e >> 5, c = e & 31;
        float s = (a == c) ? 1.0f : 0.0f;
        #pragma unroll
        for (int b = 0; b < D; ++b) s = fmaf(Lk[a * D + b], Lk[c * D + b], s);
        sA[a][c] = s;
    }
    __syncthreads();

    // Left-looking Cholesky: thread i owns row i (lrow in registers,
    // compile-time indexed). Step j publishes final row j to sLc.
    float lrow[D];
    #pragma unroll
    for (int j = 0; j < D; ++j) {
        if (i == j) {
            float s = sA[j][j];
            #pragma unroll
            for (int b = 0; b < j; ++b) s = fmaf(-lrow[b], lrow[b], s);
            const float d = sqrtf(s);
            lrow[j] = d;
            #pragma unroll
            for (int b = 0; b < j; ++b) sLc[j][b] = lrow[b];
            sLc[j][j] = d;
        }
        __syncthreads();
        if (i > j) {
            float s = sA[i][j];
            #pragma unroll
            for (int b = 0; b < j; ++b) s = fmaf(-lrow[b], sLc[j][b], s);
            lrow[j] = s / sLc[j][j];
        }
    }
    __syncthreads();

    // store Lc rows (zero-padded upper) for setup2
    #pragma unroll
    for (int b = 0; b < D; ++b)
        ws[LCOFF + k * D * D + i * D + b] = (b <= i) ? lrow[b] : 0.0f;

    // invLc: thread j = i solves column j by forward substitution.
    // col[ii] = 0 for ii<j by induction; predication keeps trips compile-time.
    {
        const int j = i;
        float col[D];
        #pragma unroll
        for (int ii = 0; ii < D; ++ii) {
            float s = (ii == j) ? 1.0f : 0.0f;
            #pragma unroll
            for (int b = 0; b < ii; ++b) {
                const float m = (b >= j) ? sLc[ii][b] : 0.0f;
                s = fmaf(-m, col[b], s);
            }
            col[ii] = s / sLc[ii][ii];
            ws[MOFF + k * D * D + ii * D + j] = col[ii];   // coalesced over j
        }
        // stash invLc into sA (reused) for the w_k dot
        #pragma unroll
        for (int ii = 0; ii < D; ++ii) sA[ii][j] = col[ii];
    }
    __syncthreads();

    // w_k[i] = sum_b invLc[i][b] * mu[k][b]
    {
        float s = 0.0f;
        #pragma unroll
        for (int b = 0; b < D; ++b) s = fmaf(sA[i][b], mu[k * D + b], s);
        ws[WOFF + k * D + i] = s;
    }
}

// ---------------------------------------------------------------------------
// setup2: pair constants. Stage Lc into LDS; 36 threads do fully-unrolled
// triangular solves (compile-time trips, runtime base addresses).
// ---------------------------------------------------------------------------
#define SLC(kk, r, c) sLc2[(kk) * 1024 + (r) * 32 + (c)]

__global__ __launch_bounds__(64) void setup2_kernel(
    const float* __restrict__ mu, const float* __restrict__ weights,
    float* __restrict__ ws)
{
    __shared__ float sLc2[K * D * D];   // 32 KB
    __shared__ float sLogw[K];
    __shared__ float sCp[NPAIR];
    __shared__ float sCmax;
    const int tid = threadIdx.x;

    {   // stage 32 KB of Lc
        const float4* src = (const float4*)(ws + LCOFF);
        float4* dst = (float4*)sLc2;
        for (int e = tid; e < K * D * D / 4; e += 64) dst[e] = src[e];
    }
    if (tid == 0) {
        float m = -INFINITY;
        for (int t = 0; t < K; ++t) m = fmaxf(m, weights[t]);
        float s = 0.0f;
        for (int t = 0; t < K; ++t) s += expf(weights[t] - m);
        const float lse = m + logf(s);
        for (int t = 0; t < K; ++t) sLogw[t] = weights[t] - lse;
    }
    __syncthreads();

    if (tid < NPAIR) {
        int tt = tid, pi = 0;
        while (tt >= (K - pi)) { tt -= (K - pi); ++pi; }
        const int pj = pi + tt;
        const float LOG2PI = 1.8378770664093453f;
        float sumlogS = 0.0f, logdetsig = 0.0f;
        #pragma unroll
        for (int r = 0; r < D; ++r) {
            const float di = SLC(pi, r, r), dj = SLC(pj, r, r);
            sumlogS += logf(di + dj);
            logdetsig -= logf(1.0f / di + 1.0f / dj);   // diag(M) = 1/di + 1/dj
        }
        // quad = -0.5 dmu^T inv(S) dmu, S = Lc_i + Lc_j lower-tri: forward solve
        float v[D];
        float quad_acc = 0.0f;
        #pragma unroll
        for (int r = 0; r < D; ++r) {
            const float d0 = mu[pi * D + r] - mu[pj * D + r];
            float s = d0;
            #pragma unroll
            for (int b = 0; b < r; ++b)
                s = fmaf(-(SLC(pi, r, b) + SLC(pj, r, b)), v[b], s);
            v[r] = s / (SLC(pi, r, r) + SLC(pj, r, r));
            quad_acc = fmaf(d0, v[r], quad_acc);
        }
        const float quad = -0.5f * quad_acc;
        float c = quad - 0.5f * sumlogS - (float)D * LOG2PI - 0.5f * logdetsig
                  + sLogw[pi] + sLogw[pj];
        if (pi < pj) c += 0.6931471805599453f;   // off-diagonal multiplicity 2
        sCp[tid] = c;
    }
    __syncthreads();
    if (tid == 0) {
        float m = -INFINITY;
        for (int t = 0; t < NPAIR; ++t) m = fmaxf(m, sCp[t]);
        sCmax = m;
        ws[CMAXOFF] = m;
    }
    __syncthreads();
    if (tid < NPAIR)
        ws[C2OFF + tid] = (sCp[tid] - sCmax) * 1.4426950408889634f;
}

// ---------------------------------------------------------------------------
// main: M/w/c2 staged in LDS (wave-uniform broadcast reads, immediate offsets,
// zero bank conflicts). Each thread processes S=2 samples so every M float4
// read feeds two independent pk-fma chains. x packed x-major in v2f.
// block=128 (2 waves), grid = nsamp/256 -> 2 blocks/CU, 4 waves/CU.
// ---------------------------------------------------------------------------
__global__ __launch_bounds__(128, 1) void main_kernel(
    const float* __restrict__ X, const float* __restrict__ cst,
    float* __restrict__ partials, int nsamp)
{
    __shared__ __align__(16) float sM[K * D * D];   // 32 KB invLc
    __shared__ float sW[K * D];
    __shared__ float sC2[NPAIR];
    __shared__ float sRed[2];
    const int tid = threadIdx.x;

    {   // stage constants
        const float4* src = (const float4*)cst;
        float4* dst = (float4*)sM;
        for (int e = tid; e < K * D * D / 4; e += 128) dst[e] = src[e];
        for (int e = tid; e < K * D; e += 128) sW[e] = cst[WOFF + e];
        if (tid < NPAIR) sC2[tid] = cst[C2OFF + tid];
    }
    __syncthreads();

    const int n0 = blockIdx.x * 256 + tid;
    const int n1 = n0 + 128;
    const bool val0 = n0 < nsamp, val1 = n1 < nsamp;
    const int m0 = val0 ? n0 : 0, m1 = val1 ? n1 : 0;

    // x for both samples, x-major v2f pairs
    v2f x0[16], x1[16];
    {
        const float4* Xv0 = (const float4*)(X + m0 * D);
        const float4* Xv1 = (const float4*)(X + m1 * D);
        #pragma unroll
        for (int q = 0; q < 8; ++q) {
            const float4 t0 = Xv0[q];
            x0[2 * q] = (v2f){t0.x, t0.y}; x0[2 * q + 1] = (v2f){t0.z, t0.w};
            const float4 t1 = Xv1[q];
            x1[2 * q] = (v2f){t1.x, t1.y}; x1[2 * q + 1] = (v2f){t1.z, t1.w};
        }
    }

    v2f G2[NPAIR];   // {G(s0), G(s1)}
    #pragma unroll
    for (int t = 0; t < NPAIR; ++t) G2[t] = (v2f){0.0f, 0.0f};

    #pragma unroll
    for (int rh = 0; rh < 8; ++rh) {
        v2f yp[K][4];                        // {y_r(s0), y_r(s1)} x 4 rows
        #pragma unroll
        for (int k = 0; k < K; ++k) {
            #pragma unroll
            for (int rr = 0; rr < 4; ++rr) {
                const int r = 4 * rh + rr;
                const float wv = sW[k * D + r];
                v2f a0 = (v2f){-wv, 0.0f};
                v2f a1 = (v2f){-wv, 0.0f};
                const float* Mr = sM + (k * D + r) * D;
                #pragma unroll
                for (int c4 = 0; c4 <= rh; ++c4) {   // uniform trip count
                    const float4 m4 = *(const float4*)(Mr + 4 * c4);
                    const v2f mlo = (v2f){m4.x, m4.y};
                    const v2f mhi = (v2f){m4.z, m4.w};
                    a0 = __builtin_elementwise_fma(mlo, x0[2 * c4], a0);
                    a0 = __builtin_elementwise_fma(mhi, x0[2 * c4 + 1], a0);
                    a1 = __builtin_elementwise_fma(mlo, x1[2 * c4], a1);
                    a1 = __builtin_elementwise_fma(mhi, x1[2 * c4 + 1], a1);
                }
                yp[k][rr] = (v2f){a0.x + a0.y, a1.x + a1.y};
            }
        }
        #pragma unroll
        for (int pi = 0; pi < K; ++pi)
            #pragma unroll
            for (int pj = pi; pj < K; ++pj) {
                v2f g = G2[gidx(pi, pj)];
                g = __builtin_elementwise_fma(yp[pi][0], yp[pj][0], g);
                g = __builtin_elementwise_fma(yp[pi][1], yp[pj][1], g);
                g = __builtin_elementwise_fma(yp[pi][2], yp[pj][2], g);
                g = __builtin_elementwise_fma(yp[pi][3], yp[pj][3], g);
                G2[gidx(pi, pj)] = g;
            }
    }

    // 36-term exp sum for both samples; q >= 0 and c2 <= 0 -> exp2 arg <= 0
    v2f acc2 = (v2f){0.0f, 0.0f};
    const float NH = -0.72134752044448170f;   // -0.5*log2(e)
    #pragma unroll
    for (int pi = 0; pi < K; ++pi)
        #pragma unroll
        for (int pj = pi; pj < K; ++pj) {
            const v2f q2 = __builtin_elementwise_fma(
                (v2f){2.0f, 2.0f}, G2[gidx(pi, pj)],
                G2[gidx(pi, pi)] + G2[gidx(pj, pj)]);
            const float c = sC2[gidx(pi, pj)];
            const v2f e2 = __builtin_elementwise_fma((v2f){NH, NH}, q2, (v2f){c, c});
            acc2.x += exp2f(e2.x);
            acc2.y += exp2f(e2.y);
        }
    float acc = (val0 ? acc2.x : 0.0f) + (val1 ? acc2.y : 0.0f);

    #pragma unroll
    for (int m = 1; m < 64; m <<= 1) acc += __shfl_xor(acc, m, 64);
    if ((tid & 63) == 0) sRed[tid >> 6] = acc;
    __syncthreads();
    if (tid == 0) partials[blockIdx.x] = sRed[0] + sRed[1];
}

__global__ __launch_bounds__(256) void finish_kernel(
    const float* __restrict__ partials, const float* __restrict__ ws,
    float* __restrict__ out, int nblk)
{
    __shared__ float sRed[4];
    const int tid = threadIdx.x;
    float acc = 0.0f;
    for (int e = tid; e < nblk; e += 256) acc += partials[e];
    #pragma unroll
    for (int m = 1; m < 64; m <<= 1) acc += __shfl_xor(acc, m, 64);
    if ((tid & 63) == 0) sRed[tid >> 6] = acc;
    __syncthreads();
    if (tid == 0) out[0] = ws[CMAXOFF] + logf(sRed[0] + sRed[1] + sRed[2] + sRed[3]);
}

extern "C" void kernel_launch(void* const* d_in, const int* in_sizes, int n_in,
                              void* d_out, int out_size, void* d_ws, size_t ws_size,
                              hipStream_t stream) {
    const float* X = (const float*)d_in[0];
    const float* mu = (const float*)d_in[1];
    const float* L = (const float*)d_in[2];
    const float* w = (const float*)d_in[3];
    float* wsf = (float*)d_ws;
    float* out = (float*)d_out;

    const int nsamp = in_sizes[0] / D;
    const int nblk = (nsamp + 255) / 256;

    setup1_kernel<<<K, 64, 0, stream>>>(mu, L, wsf);
    setup2_kernel<<<1, 64, 0, stream>>>(mu, w, wsf);
    main_kernel<<<nblk, 128, 0, stream>>>(X, wsf, wsf + PARTOFF, nsamp);
    finish_kernel<<<1, 256, 0, stream>>>(wsf + PARTOFF, wsf, out, nblk);
}

// Round 4
// 153.948 us; speedup vs baseline: 2.1167x; 1.0271x over previous
//
#include <hip/hip_runtime.h>

// Problem constants
#define D 32
#define K 8
#define NPAIR 36
#define PROWS 576              // packed (4-padded triangular) floats per matrix

// ws layout (float offsets)
#define PMOFF 0                // packed invLc, 8 x 576
#define WOFF 4608              // w_k = invLc_k mu_k, 8 x 32
#define C2OFF 4864             // (c'_t - cmax) * log2(e), 36
#define CMAXOFF 4900
#define STAGE_F4 1226          // floats 0..4903 staged into main's LDS
#define LCOFF 4928             // Lc (cholesky factors), 8 x 32 x 32, upper zeroed
#define PARTOFF 13120          // per-block partial sums (<=1024)

typedef float v2f __attribute__((ext_vector_type(2)));

__host__ __device__ constexpr int gidx(int i, int j) {  // i<=j packed pair index
    return i * 8 + j - i * (i + 1) / 2;
}
__host__ __device__ constexpr int proff(int r) {        // packed row offset
    return 4 * (r / 4 + 1) * (2 * (r / 4) + (r % 4));
}

// ---------------------------------------------------------------------------
// setup1: one 64-thread block per cluster k. Shuffle-based Cholesky (no
// per-step barriers), broadcast-LDS forward solves; <=2 live 32-float arrays
// at any point (no spills). Lanes 32-63 duplicate lanes 0-31 (benign).
// ---------------------------------------------------------------------------
__global__ __launch_bounds__(64) void setup1_kernel(
    const float* __restrict__ mu, const float* __restrict__ L,
    float* __restrict__ ws)
{
    __shared__ float sL[D][D + 1];   // L rows, later Lc rows
    __shared__ float sI[D][D + 1];   // invLc
    const int k = blockIdx.x;
    const int tid = threadIdx.x;
    const int i = tid & 31;          // row (and column) owned by this lane

    for (int e = tid; e < D * D; e += 64) sL[e >> 5][e & 31] = L[k * D * D + e];
    __syncthreads();

    // own row of L in regs
    float l[D];
    #pragma unroll
    for (int b = 0; b < D; ++b) l[b] = sL[i][b];

    // A row i: a[c] = <L_i, L_c> + (i==c); sL[c][b] uniform -> broadcast reads
    float a[D];
    #pragma unroll
    for (int c = 0; c < D; ++c) {
        float s = (i == c) ? 1.0f : 0.0f;
        #pragma unroll
        for (int b = 0; b < D; ++b) s = fmaf(l[b], sL[c][b], s);
        a[c] = s;
    }

    // Right-looking Cholesky via shuffles (lane i holds row i; no barriers).
    // At step j: pivot from lane j; lij = a[j]/sqrt(pivot) is exact for i==j too.
    float lc[D];
    #pragma unroll
    for (int j = 0; j < D; ++j) {
        const float pivot = __shfl(a[j], j, 64);
        const float dinv = 1.0f / sqrtf(pivot);
        const float lij = a[j] * dinv;
        lc[j] = lij;
        #pragma unroll
        for (int c = j + 1; c < D; ++c)
            a[c] = fmaf(-lij, __shfl(lij, c, 64), a[c]);
    }

    __syncthreads();   // done reading sL as L
    #pragma unroll
    for (int b = 0; b < D; ++b) sL[i][b] = (b <= i) ? lc[b] : 0.0f;   // publish Lc
    __syncthreads();

    // invLc: lane j=i solves column j; col[ii]=0 for ii<j by induction.
    float col[D];
    #pragma unroll
    for (int ii = 0; ii < D; ++ii) {
        float s = (ii == i) ? 1.0f : 0.0f;
        #pragma unroll
        for (int b = 0; b < ii; ++b) s = fmaf(-sL[ii][b], col[b], s);
        col[ii] = s / sL[ii][ii];
    }

    // packed M store: row ii spans [proff(ii), proff(ii)+4*(ii/4+1));
    // lane j=i writes col[ii] there (zeros fill the pad; coalesced over lanes)
    #pragma unroll
    for (int ii = 0; ii < D; ++ii) {
        const int w4 = 4 * (ii / 4 + 1);
        if (i < w4) ws[PMOFF + k * PROWS + proff(ii) + i] = col[ii];
    }

    // invLc into sI for the w_k matvec
    #pragma unroll
    for (int ii = 0; ii < D; ++ii) sI[ii][i] = col[ii];
    __syncthreads();

    // w_k[i] = sum_b invLc[i][b] * mu[k][b]  (mu broadcast via shuffle)
    {
        const float mv = mu[k * D + i];
        float s = 0.0f;
        #pragma unroll
        for (int b = 0; b < D; ++b) s = fmaf(sI[i][b], __shfl(mv, b, 64), s);
        ws[WOFF + k * D + i] = s;
    }

    // Lc rows to ws for setup2 (cooperative, coalesced)
    for (int e = tid; e < D * D; e += 64)
        ws[LCOFF + k * D * D + e] = sL[e >> 5][e & 31];
}

// ---------------------------------------------------------------------------
// setup2: pair constants from staged Lc. 36 active threads, compile-time
// trip counts, pipelined LDS reads.
// ---------------------------------------------------------------------------
#define SLC(kk, r, c) sLc2[(kk) * 1024 + (r) * 32 + (c)]

__global__ __launch_bounds__(64) void setup2_kernel(
    const float* __restrict__ mu, const float* __restrict__ weights,
    float* __restrict__ ws)
{
    __shared__ float sLc2[K * D * D];   // 32 KB
    __shared__ float sLogw[K];
    __shared__ float sCp[NPAIR];
    __shared__ float sCmax;
    const int tid = threadIdx.x;

    {   // stage 32 KB of Lc
        const float4* src = (const float4*)(ws + LCOFF);
        float4* dst = (float4*)sLc2;
        for (int e = tid; e < K * D * D / 4; e += 64) dst[e] = src[e];
    }
    if (tid == 0) {
        float m = -INFINITY;
        for (int t = 0; t < K; ++t) m = fmaxf(m, weights[t]);
        float s = 0.0f;
        for (int t = 0; t < K; ++t) s += expf(weights[t] - m);
        const float lse = m + logf(s);
        for (int t = 0; t < K; ++t) sLogw[t] = weights[t] - lse;
    }
    __syncthreads();

    if (tid < NPAIR) {
        int tt = tid, pi = 0;
        while (tt >= (K - pi)) { tt -= (K - pi); ++pi; }
        const int pj = pi + tt;
        const float LOG2PI = 1.8378770664093453f;
        float sumlogS = 0.0f, logdetsig = 0.0f;
        #pragma unroll
        for (int r = 0; r < D; ++r) {
            const float di = SLC(pi, r, r), dj = SLC(pj, r, r);
            sumlogS += logf(di + dj);
            logdetsig -= logf(1.0f / di + 1.0f / dj);   // diag(M) = 1/di + 1/dj
        }
        float v[D];
        float quad_acc = 0.0f;
        #pragma unroll
        for (int r = 0; r < D; ++r) {
            const float d0 = mu[pi * D + r] - mu[pj * D + r];
            float s = d0;
            #pragma unroll
            for (int b = 0; b < r; ++b)
                s = fmaf(-(SLC(pi, r, b) + SLC(pj, r, b)), v[b], s);
            v[r] = s / (SLC(pi, r, r) + SLC(pj, r, r));
            quad_acc = fmaf(d0, v[r], quad_acc);
        }
        const float quad = -0.5f * quad_acc;
        float c = quad - 0.5f * sumlogS - (float)D * LOG2PI - 0.5f * logdetsig
                  + sLogw[pi] + sLogw[pj];
        if (pi < pj) c += 0.6931471805599453f;   // off-diagonal multiplicity 2
        sCp[tid] = c;
    }
    __syncthreads();
    if (tid == 0) {
        float m = -INFINITY;
        for (int t = 0; t < NPAIR; ++t) m = fmaxf(m, sCp[t]);
        sCmax = m;
        ws[CMAXOFF] = m;
    }
    __syncthreads();
    if (tid < NPAIR)
        ws[C2OFF + tid] = (sCp[tid] - sCmax) * 1.4426950408889634f;
}

// ---------------------------------------------------------------------------
// main: S=1 sample/thread, 128-thr blocks, grid=nsamp/128 -> 8 waves/CU
// (2/SIMD) for latency hiding. Packed-triangular M in LDS (19.6 KB stage),
// broadcast reads with compile-time offsets; X prefetched before the barrier.
// ---------------------------------------------------------------------------
__global__ __launch_bounds__(128, 2) void main_kernel(
    const float* __restrict__ X, const float* __restrict__ cst,
    float* __restrict__ partials, int nsamp)
{
    __shared__ __align__(16) float sAll[STAGE_F4 * 4];   // 19.6 KB: pM | w | c2
    __shared__ float sRed[2];
    const int tid = threadIdx.x;
    const int n = blockIdx.x * 128 + tid;
    const bool valid = n < nsamp;
    const int m = valid ? n : 0;

    // prefetch x (global loads in flight across the staging barrier)
    v2f x[16];
    {
        const float4* Xv = (const float4*)(X + m * D);
        #pragma unroll
        for (int q = 0; q < 8; ++q) {
            const float4 t = Xv[q];
            x[2 * q] = (v2f){t.x, t.y};
            x[2 * q + 1] = (v2f){t.z, t.w};
        }
    }

    {   // stage constants (contiguous 19.6 KB)
        const float4* src = (const float4*)cst;
        float4* dst = (float4*)sAll;
        for (int e = tid; e < STAGE_F4; e += 128) dst[e] = src[e];
    }
    __syncthreads();

    v2f G2[NPAIR];   // pair Gram, packed over row-halves
    #pragma unroll
    for (int t = 0; t < NPAIR; ++t) G2[t] = (v2f){0.0f, 0.0f};

    #pragma unroll
    for (int rh = 0; rh < 8; ++rh) {
        v2f yp[K][2];                       // rows {4rh,4rh+1},{4rh+2,4rh+3}
        #pragma unroll
        for (int k = 0; k < K; ++k) {
            const float* base = sAll + k * PROWS;
            #pragma unroll
            for (int rr = 0; rr < 4; ++rr) {
                const int r = 4 * rh + rr;
                const float wv = sAll[WOFF + k * D + r];
                v2f a = (v2f){-wv, 0.0f};
                const float* Mr = base + proff(r);
                #pragma unroll
                for (int c4 = 0; c4 <= rh; ++c4) {
                    const float4 m4 = *(const float4*)(Mr + 4 * c4);
                    a = __builtin_elementwise_fma((v2f){m4.x, m4.y}, x[2 * c4], a);
                    a = __builtin_elementwise_fma((v2f){m4.z, m4.w}, x[2 * c4 + 1], a);
                }
                const float yr = a.x + a.y;
                if (rr & 1) yp[k][rr >> 1].y = yr;
                else        yp[k][rr >> 1].x = yr;
            }
        }
        #pragma unroll
        for (int pi = 0; pi < K; ++pi)
            #pragma unroll
            for (int pj = pi; pj < K; ++pj) {
                v2f g = G2[gidx(pi, pj)];
                g = __builtin_elementwise_fma(yp[pi][0], yp[pj][0], g);
                g = __builtin_elementwise_fma(yp[pi][1], yp[pj][1], g);
                G2[gidx(pi, pj)] = g;
            }
    }

    float G[NPAIR];
    #pragma unroll
    for (int t = 0; t < NPAIR; ++t) G[t] = G2[t].x + G2[t].y;

    // 36-term exp sum; q >= 0, c2 <= 0 -> exp2 arg <= 0 (no overflow)
    float acc = 0.0f;
    const float NH = -0.72134752044448170f;   // -0.5*log2(e)
    #pragma unroll
    for (int pi = 0; pi < K; ++pi)
        #pragma unroll
        for (int pj = pi; pj < K; ++pj) {
            const float q = fmaf(2.0f, G[gidx(pi, pj)], G[gidx(pi, pi)] + G[gidx(pj, pj)]);
            acc += exp2f(fmaf(NH, q, sAll[C2OFF + gidx(pi, pj)]));
        }
    if (!valid) acc = 0.0f;

    #pragma unroll
    for (int s = 1; s < 64; s <<= 1) acc += __shfl_xor(acc, s, 64);
    if ((tid & 63) == 0) sRed[tid >> 6] = acc;
    __syncthreads();
    if (tid == 0) partials[blockIdx.x] = sRed[0] + sRed[1];
}

__global__ __launch_bounds__(256) void finish_kernel(
    const float* __restrict__ partials, const float* __restrict__ ws,
    float* __restrict__ out, int nblk)
{
    __shared__ float sRed[4];
    const int tid = threadIdx.x;
    float acc = 0.0f;
    for (int e = tid; e < nblk; e += 256) acc += partials[e];
    #pragma unroll
    for (int s = 1; s < 64; s <<= 1) acc += __shfl_xor(acc, s, 64);
    if ((tid & 63) == 0) sRed[tid >> 6] = acc;
    __syncthreads();
    if (tid == 0) out[0] = ws[CMAXOFF] + logf(sRed[0] + sRed[1] + sRed[2] + sRed[3]);
}

extern "C" void kernel_launch(void* const* d_in, const int* in_sizes, int n_in,
                              void* d_out, int out_size, void* d_ws, size_t ws_size,
                              hipStream_t stream) {
    const float* X = (const float*)d_in[0];
    const float* mu = (const float*)d_in[1];
    const float* L = (const float*)d_in[2];
    const float* w = (const float*)d_in[3];
    float* wsf = (float*)d_ws;
    float* out = (float*)d_out;

    const int nsamp = in_sizes[0] / D;
    const int nblk = (nsamp + 127) / 128;

    setup1_kernel<<<K, 64, 0, stream>>>(mu, L, wsf);
    setup2_kernel<<<1, 64, 0, stream>>>(mu, w, wsf);
    main_kernel<<<nblk, 128, 0, stream>>>(X, wsf, wsf + PARTOFF, nsamp);
    finish_kernel<<<1, 256, 0, stream>>>(wsf + PARTOFF, wsf, out, nblk);
}

// Round 5
// 150.621 us; speedup vs baseline: 2.1634x; 1.0221x over previous
//
#include <hip/hip_runtime.h>

// Problem constants
#define D 32
#define K 8
#define NPAIR 36
#define PROWS 576              // packed (4-padded triangular) floats per matrix

// ws layout (float offsets)
#define PMOFF 0                // packed invLc, 8 x 576
#define WOFF 4608              // w_k = invLc_k mu_k, 8 x 32
#define C2OFF 4864             // (c'_t - cmax) * log2(e), 36
#define CMAXOFF 4900
#define STAGE_F4 1226          // floats 0..4903 staged into main's LDS
#define LCOFF 4928             // Lc (cholesky factors), 8 x 32 x 32, upper zeroed
#define PARTOFF 13120          // per-block partial sums (<=1024)

typedef float v2f __attribute__((ext_vector_type(2)));

__host__ __device__ constexpr int gidx(int i, int j) {  // i<=j packed pair index
    return i * 8 + j - i * (i + 1) / 2;
}
__host__ __device__ constexpr int proff(int r) {        // packed row offset
    return 4 * (r / 4 + 1) * (2 * (r / 4) + (r % 4));
}

// ---------------------------------------------------------------------------
// setup1: one 64-thread block per cluster k. Register discipline: at most ONE
// 32-float array live per phase (a[] updated in place through the Cholesky;
// col[] only after a[] is dead) -- prior rounds spilled at 4 live arrays.
// Lanes 32-63 duplicate lanes 0-31 (benign same-value writes).
// ---------------------------------------------------------------------------
__global__ __launch_bounds__(64) void setup1_kernel(
    const float* __restrict__ mu, const float* __restrict__ L,
    float* __restrict__ ws)
{
    __shared__ float sL[D][D + 1];    // L rows; reused later for invLc
    __shared__ float sLc[D][D + 1];   // published Cholesky rows
    const int k = blockIdx.x;
    const int tid = threadIdx.x;
    const int i = tid & 31;           // row / column owned by this lane

    for (int e = tid; e < D * D; e += 64) sL[e >> 5][e & 31] = L[k * D * D + e];
    __syncthreads();

    // Phase A: a[c] = <L_i, L_c> + (i==c); own row in regs, others broadcast.
    float a[D];
    {
        float l[D];
        #pragma unroll
        for (int b = 0; b < D; ++b) l[b] = sL[i][b];
        #pragma unroll
        for (int c = 0; c < D; ++c) {
            float s = (i == c) ? 1.0f : 0.0f;
            #pragma unroll
            for (int b = 0; b < D; ++b) s = fmaf(l[b], sL[c][b], s);
            a[c] = s;
        }
    }
    __syncthreads();   // done reading sL as L (reused below)

    // Phase B: left-looking Cholesky, in place: after step j, a[j] = Lc[i][j].
    // One barrier per step (publish -> barrier -> eliminate).
    #pragma unroll
    for (int j = 0; j < D; ++j) {
        if (i == j) {
            float s = a[j];
            #pragma unroll
            for (int b = 0; b < j; ++b) s = fmaf(-a[b], a[b], s);
            const float d = sqrtf(s);
            a[j] = d;
            #pragma unroll
            for (int b = 0; b < j; ++b) sLc[j][b] = a[b];
            sLc[j][j] = d;
        }
        __syncthreads();
        if (i > j) {
            float s = a[j];
            #pragma unroll
            for (int b = 0; b < j; ++b) s = fmaf(-a[b], sLc[j][b], s);
            a[j] = s / sLc[j][j];
        }
    }
    __syncthreads();   // all Lc rows published

    // Lc rows to ws for setup2 (upper zeroed; coalesced)
    for (int e = tid; e < D * D; e += 64) {
        const int r = e >> 5, c = e & 31;
        ws[LCOFF + k * D * D + e] = (c <= r) ? sLc[r][c] : 0.0f;
    }

    // Phase C: invLc column i by forward substitution (a[] dead, col[] live).
    // col[ii] = 0 for ii < i by induction; predication keeps trips static.
    float col[D];
    #pragma unroll
    for (int ii = 0; ii < D; ++ii) {
        float s = (ii == i) ? 1.0f : 0.0f;
        #pragma unroll
        for (int b = 0; b < ii; ++b) {
            const float m = (b >= i) ? sLc[ii][b] : 0.0f;
            s = fmaf(-m, col[b], s);
        }
        col[ii] = s / sLc[ii][ii];
    }

    // Packed M store: row ii spans [proff(ii), proff(ii)+4*(ii/4+1));
    // lane j=i writes col[ii] (zeros beyond the diagonal fill the pad).
    #pragma unroll
    for (int ii = 0; ii < D; ++ii) {
        const int w4 = 4 * (ii / 4 + 1);
        if (i < w4) ws[PMOFF + k * PROWS + proff(ii) + i] = col[ii];
    }

    // invLc into sL (reused as sI) for the w_k matvec
    #pragma unroll
    for (int ii = 0; ii < D; ++ii) sL[ii][i] = col[ii];
    __syncthreads();

    // w_k[i] = sum_b invLc[i][b] * mu[k][b]  (mu loads wave-uniform -> s_load)
    {
        float s = 0.0f;
        #pragma unroll
        for (int b = 0; b < D; ++b) s = fmaf(sL[i][b], mu[k * D + b], s);
        ws[WOFF + k * D + i] = s;
    }
}

// ---------------------------------------------------------------------------
// setup2: pair constants from staged Lc. 36 active threads, compile-time
// trip counts, pipelined LDS reads.
// ---------------------------------------------------------------------------
#define SLC(kk, r, c) sLc2[(kk) * 1024 + (r) * 32 + (c)]

__global__ __launch_bounds__(64) void setup2_kernel(
    const float* __restrict__ mu, const float* __restrict__ weights,
    float* __restrict__ ws)
{
    __shared__ float sLc2[K * D * D];   // 32 KB
    __shared__ float sLogw[K];
    __shared__ float sCp[NPAIR];
    __shared__ float sCmax;
    const int tid = threadIdx.x;

    {   // stage 32 KB of Lc
        const float4* src = (const float4*)(ws + LCOFF);
        float4* dst = (float4*)sLc2;
        for (int e = tid; e < K * D * D / 4; e += 64) dst[e] = src[e];
    }
    if (tid == 0) {
        float m = -INFINITY;
        for (int t = 0; t < K; ++t) m = fmaxf(m, weights[t]);
        float s = 0.0f;
        for (int t = 0; t < K; ++t) s += expf(weights[t] - m);
        const float lse = m + logf(s);
        for (int t = 0; t < K; ++t) sLogw[t] = weights[t] - lse;
    }
    __syncthreads();

    if (tid < NPAIR) {
        int tt = tid, pi = 0;
        while (tt >= (K - pi)) { tt -= (K - pi); ++pi; }
        const int pj = pi + tt;
        const float LOG2PI = 1.8378770664093453f;
        float sumlogS = 0.0f, logdetsig = 0.0f;
        #pragma unroll
        for (int r = 0; r < D; ++r) {
            const float di = SLC(pi, r, r), dj = SLC(pj, r, r);
            sumlogS += logf(di + dj);
            logdetsig -= logf(1.0f / di + 1.0f / dj);   // diag(M) = 1/di + 1/dj
        }
        float v[D];
        float quad_acc = 0.0f;
        #pragma unroll
        for (int r = 0; r < D; ++r) {
            const float d0 = mu[pi * D + r] - mu[pj * D + r];
            float s = d0;
            #pragma unroll
            for (int b = 0; b < r; ++b)
                s = fmaf(-(SLC(pi, r, b) + SLC(pj, r, b)), v[b], s);
            v[r] = s / (SLC(pi, r, r) + SLC(pj, r, r));
            quad_acc = fmaf(d0, v[r], quad_acc);
        }
        const float quad = -0.5f * quad_acc;
        float c = quad - 0.5f * sumlogS - (float)D * LOG2PI - 0.5f * logdetsig
                  + sLogw[pi] + sLogw[pj];
        if (pi < pj) c += 0.6931471805599453f;   // off-diagonal multiplicity 2
        sCp[tid] = c;
    }
    __syncthreads();
    if (tid == 0) {
        float m = -INFINITY;
        for (int t = 0; t < NPAIR; ++t) m = fmaxf(m, sCp[t]);
        sCmax = m;
        ws[CMAXOFF] = m;
    }
    __syncthreads();
    if (tid < NPAIR)
        ws[C2OFF + tid] = (sCp[tid] - sCmax) * 1.4426950408889634f;
}

// ---------------------------------------------------------------------------
// main: S=1 sample/thread, 128-thr blocks, grid=nsamp/128 -> 8 waves/CU
// (2/SIMD). Packed-triangular M in LDS (19.6 KB), broadcast reads with
// compile-time offsets; w loaded as one b128 per (k,rh) instead of 4 b32.
// ---------------------------------------------------------------------------
__global__ __launch_bounds__(128, 2) void main_kernel(
    const float* __restrict__ X, const float* __restrict__ cst,
    float* __restrict__ partials, int nsamp)
{
    __shared__ __align__(16) float sAll[STAGE_F4 * 4];   // 19.6 KB: pM | w | c2
    __shared__ float sRed[2];
    const int tid = threadIdx.x;
    const int n = blockIdx.x * 128 + tid;
    const bool valid = n < nsamp;
    const int m = valid ? n : 0;

    // prefetch x (global loads in flight across the staging barrier)
    v2f x[16];
    {
        const float4* Xv = (const float4*)(X + m * D);
        #pragma unroll
        for (int q = 0; q < 8; ++q) {
            const float4 t = Xv[q];
            x[2 * q] = (v2f){t.x, t.y};
            x[2 * q + 1] = (v2f){t.z, t.w};
        }
    }

    {   // stage constants (contiguous 19.6 KB)
        const float4* src = (const float4*)cst;
        float4* dst = (float4*)sAll;
        for (int e = tid; e < STAGE_F4; e += 128) dst[e] = src[e];
    }
    __syncthreads();

    v2f G2[NPAIR];   // pair Gram, packed over row-halves
    #pragma unroll
    for (int t = 0; t < NPAIR; ++t) G2[t] = (v2f){0.0f, 0.0f};

    #pragma unroll
    for (int rh = 0; rh < 8; ++rh) {
        v2f yp[K][2];                       // rows {4rh,4rh+1},{4rh+2,4rh+3}
        #pragma unroll
        for (int k = 0; k < K; ++k) {
            const float* base = sAll + k * PROWS;
            const float4 w4v = *(const float4*)(sAll + WOFF + k * D + 4 * rh);
            #pragma unroll
            for (int rr = 0; rr < 4; ++rr) {
                const int r = 4 * rh + rr;
                const float wv = (rr == 0) ? w4v.x : (rr == 1) ? w4v.y
                               : (rr == 2) ? w4v.z : w4v.w;
                v2f a = (v2f){-wv, 0.0f};
                const float* Mr = base + proff(r);
                #pragma unroll
                for (int c4 = 0; c4 <= rh; ++c4) {
                    const float4 m4 = *(const float4*)(Mr + 4 * c4);
                    a = __builtin_elementwise_fma((v2f){m4.x, m4.y}, x[2 * c4], a);
                    a = __builtin_elementwise_fma((v2f){m4.z, m4.w}, x[2 * c4 + 1], a);
                }
                const float yr = a.x + a.y;
                if (rr & 1) yp[k][rr >> 1].y = yr;
                else        yp[k][rr >> 1].x = yr;
            }
        }
        #pragma unroll
        for (int pi = 0; pi < K; ++pi)
            #pragma unroll
            for (int pj = pi; pj < K; ++pj) {
                v2f g = G2[gidx(pi, pj)];
                g = __builtin_elementwise_fma(yp[pi][0], yp[pj][0], g);
                g = __builtin_elementwise_fma(yp[pi][1], yp[pj][1], g);
                G2[gidx(pi, pj)] = g;
            }
    }

    float G[NPAIR];
    #pragma unroll
    for (int t = 0; t < NPAIR; ++t) G[t] = G2[t].x + G2[t].y;

    // 36-term exp sum; q >= 0, c2 <= 0 -> exp2 arg <= 0 (no overflow)
    float acc = 0.0f;
    const float NH = -0.72134752044448170f;   // -0.5*log2(e)
    #pragma unroll
    for (int pi = 0; pi < K; ++pi)
        #pragma unroll
        for (int pj = pi; pj < K; ++pj) {
            const float q = fmaf(2.0f, G[gidx(pi, pj)], G[gidx(pi, pi)] + G[gidx(pj, pj)]);
            acc += exp2f(fmaf(NH, q, sAll[C2OFF + gidx(pi, pj)]));
        }
    if (!valid) acc = 0.0f;

    #pragma unroll
    for (int s = 1; s < 64; s <<= 1) acc += __shfl_xor(acc, s, 64);
    if ((tid & 63) == 0) sRed[tid >> 6] = acc;
    __syncthreads();
    if (tid == 0) partials[blockIdx.x] = sRed[0] + sRed[1];
}

__global__ __launch_bounds__(256) void finish_kernel(
    const float* __restrict__ partials, const float* __restrict__ ws,
    float* __restrict__ out, int nblk)
{
    __shared__ float sRed[4];
    const int tid = threadIdx.x;
    float acc = 0.0f;
    for (int e = tid; e < nblk; e += 256) acc += partials[e];
    #pragma unroll
    for (int s = 1; s < 64; s <<= 1) acc += __shfl_xor(acc, s, 64);
    if ((tid & 63) == 0) sRed[tid >> 6] = acc;
    __syncthreads();
    if (tid == 0) out[0] = ws[CMAXOFF] + logf(sRed[0] + sRed[1] + sRed[2] + sRed[3]);
}

extern "C" void kernel_launch(void* const* d_in, const int* in_sizes, int n_in,
                              void* d_out, int out_size, void* d_ws, size_t ws_size,
                              hipStream_t stream) {
    const float* X = (const float*)d_in[0];
    const float* mu = (const float*)d_in[1];
    const float* L = (const float*)d_in[2];
    const float* w = (const float*)d_in[3];
    float* wsf = (float*)d_ws;
    float* out = (float*)d_out;

    const int nsamp = in_sizes[0] / D;
    const int nblk = (nsamp + 127) / 128;

    setup1_kernel<<<K, 64, 0, stream>>>(mu, L, wsf);
    setup2_kernel<<<1, 64, 0, stream>>>(mu, w, wsf);
    main_kernel<<<nblk, 128, 0, stream>>>(X, wsf, wsf + PARTOFF, nsamp);
    finish_kernel<<<1, 256, 0, stream>>>(wsf + PARTOFF, wsf, out, nblk);
}